// Round 14
// baseline (254.550 us; speedup 1.0000x reference)
//
#include <hip/hip_runtime.h>

// out[n,k] = d[k] + sum_{ji,c} Bmat[k*49+ji][c] * bilinear_ji(proj[n,c,:,:])
// Bmat = WH·(w3·w2·w1); boxes constant -> whole pipeline linear in proj.
//
// Launches: k_prepA (Y, T1, bias-chain; 513 blocks) -> k_prepB (Bmat) ->
//           k_mainf (fused bilinear+dot over proj; 16384 blocks) -> k_reduce.
//
// ws layout (floats):
//   Y    [512][512]    off 0
//   T1   [490][512]    off 262144
//   Bmat [490][512]    off 513024
//   dvec [16]          off 763904
//   part [16384*4][10] off 763920

#define CHW4 25088   // float4 per proj row
#define STEP 1.8571428571428572f  // 13/7

// Phase A: blocks 0-255: Y = w2*w1. blocks 256-511: T1 = WH*w3 (WH gathered
// from w_note/w_reg on the fly). block 512: bias chain -> dvec[10].
__global__ __launch_bounds__(256) void k_prepA(
    const float* __restrict__ w1, const float* __restrict__ w2,
    const float* __restrict__ w3,
    const float* __restrict__ w_note, const float* __restrict__ w_reg,
    const float* __restrict__ b1, const float* __restrict__ b2,
    const float* __restrict__ b3,
    const float* __restrict__ b_note, const float* __restrict__ b_reg,
    float* __restrict__ Y, float* __restrict__ T1, float* __restrict__ dvec) {
    __shared__ float As[32][36];
    __shared__ float Bs[32][36];
    int blk = blockIdx.x;
    int tid = threadIdx.x;

    if (blk < 512) {
        bool isY = blk < 256;
        int t = blk & 255;
        int bx = t & 15, by = t >> 4;
        int lr = tid >> 3, lc = (tid & 7) << 2;
        int tx = tid & 15, ty = tid >> 4;
        const float* Bsrc = isY ? w1 : w3;
        float* C = isY ? Y : T1;
        int M = isY ? 512 : 490;
        int gr = by * 32 + lr;
        const float* whrow = nullptr;
        int ji = 0;
        if (!isY && gr < 490) {
            int k = gr / 49; ji = gr - k * 49;
            whrow = (k < 2) ? (w_note + k * 25088) : (w_reg + (k - 2) * 25088);
        }
        float a00 = 0.f, a01 = 0.f, a10 = 0.f, a11 = 0.f;
        for (int kc = 0; kc < 512; kc += 32) {
            float4 av = make_float4(0.f, 0.f, 0.f, 0.f);
            if (isY) {
                av = *(const float4*)&w2[(size_t)gr * 512 + kc + lc];
            } else if (whrow) {
                av.x = whrow[(kc + lc + 0) * 49 + ji];
                av.y = whrow[(kc + lc + 1) * 49 + ji];
                av.z = whrow[(kc + lc + 2) * 49 + ji];
                av.w = whrow[(kc + lc + 3) * 49 + ji];
            }
            *(float4*)&As[lr][lc] = av;
            *(float4*)&Bs[lr][lc] = *(const float4*)&Bsrc[(size_t)(kc + lr) * 512 + bx * 32 + lc];
            __syncthreads();
            #pragma unroll
            for (int kk = 0; kk < 32; ++kk) {
                float b0 = Bs[kk][tx * 2], b1v = Bs[kk][tx * 2 + 1];
                float x0 = As[ty * 2][kk], x1 = As[ty * 2 + 1][kk];
                a00 += x0 * b0; a01 += x0 * b1v;
                a10 += x1 * b0; a11 += x1 * b1v;
            }
            __syncthreads();
        }
        int r0 = by * 32 + ty * 2, c0 = bx * 32 + tx * 2;
        if (r0 < M)     { C[(size_t)r0 * 512 + c0] = a00; C[(size_t)r0 * 512 + c0 + 1] = a01; }
        if (r0 + 1 < M) { C[(size_t)(r0 + 1) * 512 + c0] = a10; C[(size_t)(r0 + 1) * 512 + c0 + 1] = a11; }
    } else {
        // bias chain: u2 = b2 + w2*b1; vv = b3 + w3*u2; dvec[k] = bh[k] + wh[k]·vv[i/49]
        __shared__ float u2[512], vv[512], red[256];
        for (int o = tid; o < 512; o += 256) {
            float s = 0.f;
            for (int i = 0; i < 512; ++i) s += w2[(size_t)o * 512 + i] * b1[i];
            u2[o] = b2[o] + s;
        }
        __syncthreads();
        for (int o = tid; o < 512; o += 256) {
            float s = 0.f;
            for (int i = 0; i < 512; ++i) s += w3[(size_t)o * 512 + i] * u2[i];
            vv[o] = b3[o] + s;
        }
        __syncthreads();
        float sk[10];
        #pragma unroll
        for (int k = 0; k < 10; ++k) {
            const float* wh = (k < 2) ? (w_note + k * 25088) : (w_reg + (k - 2) * 25088);
            float s = 0.f;
            for (int i = tid; i < 25088; i += 256) s += wh[i] * vv[i / 49];
            sk[k] = s;
        }
        #pragma unroll 1
        for (int k = 0; k < 10; ++k) {
            red[tid] = sk[k];
            __syncthreads();
            for (int off = 128; off; off >>= 1) {
                if (tid < off) red[tid] += red[tid + off];
                __syncthreads();
            }
            if (tid == 0) dvec[k] = red[0] + ((k < 2) ? b_note[k] : b_reg[k - 2]);
            __syncthreads();
        }
    }
}

// Phase B: Bmat = T1 * Y  (490 x 512)
__global__ __launch_bounds__(256) void k_prepB(const float* __restrict__ T1,
                                               const float* __restrict__ Y,
                                               float* __restrict__ Bmat) {
    __shared__ float As[32][36];
    __shared__ float Bs[32][36];
    int bx = blockIdx.x & 15, by = blockIdx.x >> 4;
    int tid = threadIdx.x;
    int lr = tid >> 3, lc = (tid & 7) << 2;
    int tx = tid & 15, ty = tid >> 4;
    int gr = by * 32 + lr;
    float a00 = 0.f, a01 = 0.f, a10 = 0.f, a11 = 0.f;
    for (int kc = 0; kc < 512; kc += 32) {
        float4 av = make_float4(0.f, 0.f, 0.f, 0.f);
        if (gr < 490) av = *(const float4*)&T1[(size_t)gr * 512 + kc + lc];
        *(float4*)&As[lr][lc] = av;
        *(float4*)&Bs[lr][lc] = *(const float4*)&Y[(size_t)(kc + lr) * 512 + bx * 32 + lc];
        __syncthreads();
        #pragma unroll
        for (int kk = 0; kk < 32; ++kk) {
            float b0 = Bs[kk][tx * 2], b1v = Bs[kk][tx * 2 + 1];
            float x0 = As[ty * 2][kk], x1 = As[ty * 2 + 1][kk];
            a00 += x0 * b0; a01 += x0 * b1v;
            a10 += x1 * b0; a11 += x1 * b1v;
        }
        __syncthreads();
    }
    int r0 = by * 32 + ty * 2, c0 = bx * 32 + tx * 2;
    if (r0 < 490)     { Bmat[(size_t)r0 * 512 + c0] = a00; Bmat[(size_t)r0 * 512 + c0 + 1] = a01; }
    if (r0 + 1 < 490) { Bmat[(size_t)(r0 + 1) * 512 + c0] = a10; Bmat[(size_t)(r0 + 1) * 512 + c0 + 1] = a11; }
}

// Fused main: block b = n*32+ch (16 channels). Stage 12.25 KB contiguous ->
// LDS (batched loads first), bilinear inline, dot vs 10 Bmat slices (L2),
// butterfly reduce, per-wave partial store.
__global__ __launch_bounds__(256) void k_mainf(const float* __restrict__ proj,
                                               const float* __restrict__ Bmat,
                                               float* __restrict__ part) {
    __shared__ float X[16][197];   // 12,608 B; stride 197 -> conflict-free
    int b = blockIdx.x;            // 0..16383
    int n = b >> 5;
    int ch = b & 31;               // c0 = ch*16
    int tid = threadIdx.x;
    int wv = tid >> 6, lane = tid & 63;

    const float4* src = (const float4*)proj + (size_t)n * CHW4 + ch * 784;
    // batched loads: all issued before any LDS write
    float4 v0 = src[tid];
    float4 v1 = src[tid + 256];
    float4 v2 = src[tid + 512];
    float4 v3;
    if (tid < 16) v3 = src[tid + 768];

    // scatter to LDS with incremental (cc,q): index i = tid + s*256, i = cc*49+q
    int cc = tid / 49, q = tid - (tid / 49) * 49;
    {
        float* xr = &X[cc][q * 4];
        xr[0] = v0.x; xr[1] = v0.y; xr[2] = v0.z; xr[3] = v0.w;
    }
    cc += 5; q += 11; if (q >= 49) { q -= 49; ++cc; }
    {
        float* xr = &X[cc][q * 4];
        xr[0] = v1.x; xr[1] = v1.y; xr[2] = v1.z; xr[3] = v1.w;
    }
    cc += 5; q += 11; if (q >= 49) { q -= 49; ++cc; }
    {
        float* xr = &X[cc][q * 4];
        xr[0] = v2.x; xr[1] = v2.y; xr[2] = v2.z; xr[3] = v2.w;
    }
    if (tid < 16) {
        // i = tid + 768 -> cc = 15, q = tid + 33 (no carry for tid<16)
        float* xr = &X[15][(tid + 33) * 4];
        xr[0] = v3.x; xr[1] = v3.y; xr[2] = v3.z; xr[3] = v3.w;
    }
    __syncthreads();

    const float base = STEP * 0.5f - 0.5f;
    float acc[10];
    #pragma unroll
    for (int k = 0; k < 10; ++k) acc[k] = 0.f;

    #pragma unroll
    for (int s = 0; s < 3; ++s) {
        int o = tid + s * 256;         // elem = ji*16 + cl, 784 total
        int ji = o >> 4, cl = o & 15;
        int j = (ji * 37) >> 8;        // floor(ji/7) for ji<49
        int i2 = ji - j * 7;
        float yv = base + j * STEP;
        float xv = base + i2 * STEP;
        float y0f = floorf(yv), x0f = floorf(xv);
        float wy = yv - y0f, wx = xv - x0f;
        int i00 = (int)y0f * 14 + (int)x0f;
        const float* xr = X[cl];
        float v00 = xr[i00],      v01 = xr[i00 + 1];
        float v10 = xr[i00 + 14], v11 = xr[i00 + 15];
        float top = v00 + (v01 - v00) * wx;
        float bot = v10 + (v11 - v10) * wx;
        float v = top + (bot - top) * wy;
        int bidx = (ji << 9) + (ch << 4) + cl;
        #pragma unroll
        for (int k = 0; k < 10; ++k)
            acc[k] += v * Bmat[(size_t)k * 25088 + bidx];
    }
    if (tid < 16) {
        int o = tid + 768;
        int ji = o >> 4, cl = o & 15;  // ji = 48
        int j = (ji * 37) >> 8;
        int i2 = ji - j * 7;
        float yv = base + j * STEP;
        float xv = base + i2 * STEP;
        float y0f = floorf(yv), x0f = floorf(xv);
        float wy = yv - y0f, wx = xv - x0f;
        int i00 = (int)y0f * 14 + (int)x0f;
        const float* xr = X[cl];
        float v00 = xr[i00],      v01 = xr[i00 + 1];
        float v10 = xr[i00 + 14], v11 = xr[i00 + 15];
        float top = v00 + (v01 - v00) * wx;
        float bot = v10 + (v11 - v10) * wx;
        float v = top + (bot - top) * wy;
        int bidx = (ji << 9) + (ch << 4) + cl;
        #pragma unroll
        for (int k = 0; k < 10; ++k)
            acc[k] += v * Bmat[(size_t)k * 25088 + bidx];
    }

    #pragma unroll
    for (int k = 0; k < 10; ++k) {
        float v = acc[k];
        v += __shfl_xor(v, 1);
        v += __shfl_xor(v, 2);
        v += __shfl_xor(v, 4);
        v += __shfl_xor(v, 8);
        v += __shfl_xor(v, 16);
        v += __shfl_xor(v, 32);
        if (lane == k) part[((size_t)b * 4 + wv) * 10 + k] = v;
    }
}

// out[n,k] = dvec[k] + sum over 128 wave-partials (32 ch x 4 wv)
__global__ void k_reduce(const float* __restrict__ part,
                         const float* __restrict__ dvec,
                         float* __restrict__ out) {
    int idx = blockIdx.x * 256 + threadIdx.x;  // 0..5119
    int n = idx / 10, k = idx % 10;
    float s = dvec[k];
    for (int w = 0; w < 128; ++w) s += part[((size_t)n * 128 + w) * 10 + k];
    if (k < 2) out[n * 2 + k] = s;
    else       out[1024 + n * 8 + (k - 2)] = s;
}

extern "C" void kernel_launch(void* const* d_in, const int* in_sizes, int n_in,
                              void* d_out, int out_size, void* d_ws, size_t ws_size,
                              hipStream_t stream) {
    const float* proj   = (const float*)d_in[0];
    const float* w1     = (const float*)d_in[1];
    const float* b1     = (const float*)d_in[2];
    const float* w2     = (const float*)d_in[3];
    const float* b2     = (const float*)d_in[4];
    const float* w3     = (const float*)d_in[5];
    const float* b3     = (const float*)d_in[6];
    const float* w_note = (const float*)d_in[7];
    const float* b_note = (const float*)d_in[8];
    const float* w_reg  = (const float*)d_in[9];
    const float* b_reg  = (const float*)d_in[10];

    float* ws   = (float*)d_ws;
    float* Y    = ws;
    float* T1   = Y + 262144;
    float* Bmat = T1 + 250880;
    float* dvec = Bmat + 250880;
    float* part = dvec + 16;
    float* out  = (float*)d_out;

    k_prepA<<<513, 256, 0, stream>>>(w1, w2, w3, w_note, w_reg,
                                     b1, b2, b3, b_note, b_reg, Y, T1, dvec);
    k_prepB<<<256, 256, 0, stream>>>(T1, Y, Bmat);
    k_mainf<<<16384, 256, 0, stream>>>(proj, Bmat, part);
    k_reduce<<<20, 256, 0, stream>>>(part, dvec, out);
}

// Round 15
// 129.564 us; speedup vs baseline: 1.9647x; 1.9647x over previous
//
#include <hip/hip_runtime.h>

// out[n,k] = d[k] + sum_{ji,c} Bmat[k*49+ji][c] * bilinear_ji(proj[n,c,:,:])
// Bmat = WH·(w3·w2·w1); boxes constant -> whole pipeline linear in proj.
//
// Prep (round-13 proven, ~27us): k_whT || k_mmb {Y=w2*w1, T1=WH*w3} ->
//   k_mm32 Bmat=T1*Y; bias chain k_mv1 -> k_mv2 -> k_dvec (parallel grids).
// Main (round-14 proven, ~78us): fused 16-channel bilinear+dot, 16384 blocks.
//
// ws layout (floats):
//   WH    [490][512]   off 0
//   Y     [512][512]   off 250880
//   T1    [490][512]   off 513024
//   Bmat  [490][512]   off 763904
//   u2    [512]        off 1014784
//   vv    [512]        off 1015296
//   dpart [10][8]      off 1015808
//   part  [16384*4][10] off 1015888

#define CHW4 25088   // float4 per proj row
#define STEP 1.8571428571428572f  // 13/7

// C[M x 512] = A[M x 512] * B[512 x 512]; 32x32 tile, 2x2/thread.
__global__ __launch_bounds__(256) void k_mm32(const float* __restrict__ A,
                                              const float* __restrict__ B,
                                              float* __restrict__ C, int M) {
    __shared__ float As[32][36];
    __shared__ float Bs[32][36];
    int bx = blockIdx.x, by = blockIdx.y;
    int tid = threadIdx.x;
    int lr = tid >> 3;
    int lc = (tid & 7) << 2;
    int tx = tid & 15, ty = tid >> 4;
    float a00 = 0.f, a01 = 0.f, a10 = 0.f, a11 = 0.f;
    for (int kc = 0; kc < 512; kc += 32) {
        int gr = by * 32 + lr;
        float4 av = make_float4(0.f, 0.f, 0.f, 0.f);
        if (gr < M) av = *(const float4*)&A[(size_t)gr * 512 + kc + lc];
        *(float4*)&As[lr][lc] = av;
        float4 bv = *(const float4*)&B[(size_t)(kc + lr) * 512 + bx * 32 + lc];
        *(float4*)&Bs[lr][lc] = bv;
        __syncthreads();
        #pragma unroll
        for (int kk = 0; kk < 32; ++kk) {
            float b0 = Bs[kk][tx * 2], b1 = Bs[kk][tx * 2 + 1];
            float x0 = As[ty * 2][kk], x1 = As[ty * 2 + 1][kk];
            a00 += x0 * b0; a01 += x0 * b1;
            a10 += x1 * b0; a11 += x1 * b1;
        }
        __syncthreads();
    }
    int r0 = by * 32 + ty * 2, c0 = bx * 32 + tx * 2;
    if (r0 < M)     { C[(size_t)r0 * 512 + c0] = a00; C[(size_t)r0 * 512 + c0 + 1] = a01; }
    if (r0 + 1 < M) { C[(size_t)(r0 + 1) * 512 + c0] = a10; C[(size_t)(r0 + 1) * 512 + c0 + 1] = a11; }
}

// Batched level-1: z=0 -> Y = w2*w1 (M=512); z=1 -> T1 = WH*w3 (M=490).
__global__ __launch_bounds__(256) void k_mmb(const float* __restrict__ w1,
                                             const float* __restrict__ w2,
                                             const float* __restrict__ w3,
                                             const float* __restrict__ WH,
                                             float* __restrict__ Y,
                                             float* __restrict__ T1) {
    __shared__ float As[32][36];
    __shared__ float Bs[32][36];
    const float* A; const float* B; float* C; int M;
    if (blockIdx.z == 0) { A = w2; B = w1; C = Y;  M = 512; }
    else                 { A = WH; B = w3; C = T1; M = 490; }
    int bx = blockIdx.x, by = blockIdx.y;
    int tid = threadIdx.x;
    int lr = tid >> 3;
    int lc = (tid & 7) << 2;
    int tx = tid & 15, ty = tid >> 4;
    float a00 = 0.f, a01 = 0.f, a10 = 0.f, a11 = 0.f;
    for (int kc = 0; kc < 512; kc += 32) {
        int gr = by * 32 + lr;
        float4 av = make_float4(0.f, 0.f, 0.f, 0.f);
        if (gr < M) av = *(const float4*)&A[(size_t)gr * 512 + kc + lc];
        *(float4*)&As[lr][lc] = av;
        float4 bv = *(const float4*)&B[(size_t)(kc + lr) * 512 + bx * 32 + lc];
        *(float4*)&Bs[lr][lc] = bv;
        __syncthreads();
        #pragma unroll
        for (int kk = 0; kk < 32; ++kk) {
            float b0 = Bs[kk][tx * 2], b1 = Bs[kk][tx * 2 + 1];
            float x0 = As[ty * 2][kk], x1 = As[ty * 2 + 1][kk];
            a00 += x0 * b0; a01 += x0 * b1;
            a10 += x1 * b0; a11 += x1 * b1;
        }
        __syncthreads();
    }
    int r0 = by * 32 + ty * 2, c0 = bx * 32 + tx * 2;
    if (r0 < M)     { C[(size_t)r0 * 512 + c0] = a00; C[(size_t)r0 * 512 + c0 + 1] = a01; }
    if (r0 + 1 < M) { C[(size_t)(r0 + 1) * 512 + c0] = a10; C[(size_t)(r0 + 1) * 512 + c0 + 1] = a11; }
}

// WH[r][q] = wh[k][q*49 + ji],  r = k*49 + ji
__global__ void k_whT(const float* __restrict__ w_note, const float* __restrict__ w_reg,
                      float* __restrict__ WH) {
    int r = blockIdx.x;      // 0..489
    int q = threadIdx.x;     // 0..511
    int k = r / 49, ji = r % 49;
    const float* wh = (k < 2) ? (w_note + k * 25088) : (w_reg + (k - 2) * 25088);
    WH[(size_t)r * 512 + q] = wh[q * 49 + ji];
}

// u2 = b2 + w2*b1
__global__ void k_mv1(const float* __restrict__ w2, const float* __restrict__ b1,
                      const float* __restrict__ b2, float* __restrict__ u2) {
    int o = blockIdx.x;
    int l = threadIdx.x;  // 64
    float s = 0.f;
    for (int i = l; i < 512; i += 64) s += w2[(size_t)o * 512 + i] * b1[i];
    for (int off = 32; off; off >>= 1) s += __shfl_down(s, off);
    if (l == 0) u2[o] = b2[o] + s;
}

// vv = b3 + w3*u2
__global__ void k_mv2(const float* __restrict__ w3, const float* __restrict__ u2,
                      const float* __restrict__ b3, float* __restrict__ vv) {
    int o = blockIdx.x;
    int l = threadIdx.x;  // 64
    float s = 0.f;
    for (int i = l; i < 512; i += 64) s += w3[(size_t)o * 512 + i] * u2[i];
    for (int off = 32; off; off >>= 1) s += __shfl_down(s, off);
    if (l == 0) vv[o] = b3[o] + s;
}

// dpart[k][b] = partial of sum_i wh[k][i] * vv[i/49]
__global__ void k_dvec(const float* __restrict__ w_note, const float* __restrict__ w_reg,
                       const float* __restrict__ vv, float* __restrict__ dpart) {
    int k = blockIdx.x;   // 10
    int b = blockIdx.y;   // 8
    int t = threadIdx.x;  // 256
    const float* wh = (k < 2) ? (w_note + k * 25088) : (w_reg + (k - 2) * 25088);
    float s = 0.f;
    for (int i = b * 256 + t; i < 25088; i += 2048) s += wh[i] * vv[i / 49];
    __shared__ float red[256];
    red[t] = s;
    __syncthreads();
    for (int off = 128; off; off >>= 1) {
        if (t < off) red[t] += red[t + off];
        __syncthreads();
    }
    if (t == 0) dpart[k * 8 + b] = red[0];
}

// Fused main: block b = n*32+ch (16 channels). Stage 12.25 KB contiguous ->
// LDS (batched loads first), bilinear inline, dot vs 10 Bmat slices (L2),
// butterfly reduce, per-wave partial store.
__global__ __launch_bounds__(256) void k_mainf(const float* __restrict__ proj,
                                               const float* __restrict__ Bmat,
                                               float* __restrict__ part) {
    __shared__ float X[16][197];   // 12,608 B; stride 197 -> conflict-free
    int b = blockIdx.x;            // 0..16383
    int n = b >> 5;
    int ch = b & 31;               // c0 = ch*16
    int tid = threadIdx.x;
    int wv = tid >> 6, lane = tid & 63;

    const float4* src = (const float4*)proj + (size_t)n * CHW4 + ch * 784;
    float4 v0 = src[tid];
    float4 v1 = src[tid + 256];
    float4 v2 = src[tid + 512];
    float4 v3;
    if (tid < 16) v3 = src[tid + 768];

    int cc = tid / 49, q = tid - (tid / 49) * 49;
    {
        float* xr = &X[cc][q * 4];
        xr[0] = v0.x; xr[1] = v0.y; xr[2] = v0.z; xr[3] = v0.w;
    }
    cc += 5; q += 11; if (q >= 49) { q -= 49; ++cc; }
    {
        float* xr = &X[cc][q * 4];
        xr[0] = v1.x; xr[1] = v1.y; xr[2] = v1.z; xr[3] = v1.w;
    }
    cc += 5; q += 11; if (q >= 49) { q -= 49; ++cc; }
    {
        float* xr = &X[cc][q * 4];
        xr[0] = v2.x; xr[1] = v2.y; xr[2] = v2.z; xr[3] = v2.w;
    }
    if (tid < 16) {
        float* xr = &X[15][(tid + 33) * 4];
        xr[0] = v3.x; xr[1] = v3.y; xr[2] = v3.z; xr[3] = v3.w;
    }
    __syncthreads();

    const float base = STEP * 0.5f - 0.5f;
    float acc[10];
    #pragma unroll
    for (int k = 0; k < 10; ++k) acc[k] = 0.f;

    #pragma unroll
    for (int s = 0; s < 3; ++s) {
        int o = tid + s * 256;         // elem = ji*16 + cl, 784 total
        int ji = o >> 4, cl = o & 15;
        int j = (ji * 37) >> 8;        // floor(ji/7) for ji<49
        int i2 = ji - j * 7;
        float yv = base + j * STEP;
        float xv = base + i2 * STEP;
        float y0f = floorf(yv), x0f = floorf(xv);
        float wy = yv - y0f, wx = xv - x0f;
        int i00 = (int)y0f * 14 + (int)x0f;
        const float* xr = X[cl];
        float v00 = xr[i00],      v01 = xr[i00 + 1];
        float v10 = xr[i00 + 14], v11 = xr[i00 + 15];
        float top = v00 + (v01 - v00) * wx;
        float bot = v10 + (v11 - v10) * wx;
        float v = top + (bot - top) * wy;
        int bidx = (ji << 9) + (ch << 4) + cl;
        #pragma unroll
        for (int k = 0; k < 10; ++k)
            acc[k] += v * Bmat[(size_t)k * 25088 + bidx];
    }
    if (tid < 16) {
        int o = tid + 768;
        int ji = o >> 4, cl = o & 15;  // ji = 48
        int j = (ji * 37) >> 8;
        int i2 = ji - j * 7;
        float yv = base + j * STEP;
        float xv = base + i2 * STEP;
        float y0f = floorf(yv), x0f = floorf(xv);
        float wy = yv - y0f, wx = xv - x0f;
        int i00 = (int)y0f * 14 + (int)x0f;
        const float* xr = X[cl];
        float v00 = xr[i00],      v01 = xr[i00 + 1];
        float v10 = xr[i00 + 14], v11 = xr[i00 + 15];
        float top = v00 + (v01 - v00) * wx;
        float bot = v10 + (v11 - v10) * wx;
        float v = top + (bot - top) * wy;
        int bidx = (ji << 9) + (ch << 4) + cl;
        #pragma unroll
        for (int k = 0; k < 10; ++k)
            acc[k] += v * Bmat[(size_t)k * 25088 + bidx];
    }

    #pragma unroll
    for (int k = 0; k < 10; ++k) {
        float v = acc[k];
        v += __shfl_xor(v, 1);
        v += __shfl_xor(v, 2);
        v += __shfl_xor(v, 4);
        v += __shfl_xor(v, 8);
        v += __shfl_xor(v, 16);
        v += __shfl_xor(v, 32);
        if (lane == k) part[((size_t)b * 4 + wv) * 10 + k] = v;
    }
}

// out[n,k] = bias + dpart-sum + sum over 128 wave-partials (32 ch x 4 wv)
__global__ void k_reduce(const float* __restrict__ part,
                         const float* __restrict__ dpart,
                         const float* __restrict__ b_note, const float* __restrict__ b_reg,
                         float* __restrict__ out) {
    int idx = blockIdx.x * 256 + threadIdx.x;  // 0..5119
    int n = idx / 10, k = idx % 10;
    float s = (k < 2) ? b_note[k] : b_reg[k - 2];
    for (int b = 0; b < 8; ++b) s += dpart[k * 8 + b];
    for (int w = 0; w < 128; ++w) s += part[((size_t)n * 128 + w) * 10 + k];
    if (k < 2) out[n * 2 + k] = s;
    else       out[1024 + n * 8 + (k - 2)] = s;
}

extern "C" void kernel_launch(void* const* d_in, const int* in_sizes, int n_in,
                              void* d_out, int out_size, void* d_ws, size_t ws_size,
                              hipStream_t stream) {
    const float* proj   = (const float*)d_in[0];
    const float* w1     = (const float*)d_in[1];
    const float* b1     = (const float*)d_in[2];
    const float* w2     = (const float*)d_in[3];
    const float* b2     = (const float*)d_in[4];
    const float* w3     = (const float*)d_in[5];
    const float* b3     = (const float*)d_in[6];
    const float* w_note = (const float*)d_in[7];
    const float* b_note = (const float*)d_in[8];
    const float* w_reg  = (const float*)d_in[9];
    const float* b_reg  = (const float*)d_in[10];

    float* ws    = (float*)d_ws;
    float* WH    = ws;
    float* Y     = WH + 250880;
    float* T1    = Y + 262144;
    float* Bmat  = T1 + 250880;
    float* u2    = Bmat + 250880;
    float* vv    = u2 + 512;
    float* dpart = vv + 512;
    float* part  = dpart + 80;
    float* out   = (float*)d_out;

    k_whT<<<490, 512, 0, stream>>>(w_note, w_reg, WH);
    k_mmb<<<dim3(16, 16, 2), 256, 0, stream>>>(w1, w2, w3, WH, Y, T1);
    k_mm32<<<dim3(16, 16), 256, 0, stream>>>(T1, Y, Bmat, 490);
    k_mv1<<<512, 64, 0, stream>>>(w2, b1, b2, u2);
    k_mv2<<<512, 64, 0, stream>>>(w3, u2, b3, vv);
    k_dvec<<<dim3(10, 8), 256, 0, stream>>>(w_note, w_reg, vv, dpart);
    k_mainf<<<16384, 256, 0, stream>>>(proj, Bmat, part);
    k_reduce<<<20, 256, 0, stream>>>(part, dpart, b_note, b_reg, out);
}

// Round 16
// 95.371 us; speedup vs baseline: 2.6690x; 1.3585x over previous
//
#include <hip/hip_runtime.h>

// out[n,k] = d[k] + sum_{ji,c} Bmat[k*49+ji][c] * bilinear_ji(proj[n,c,:,:])
// Bmat = WH·(w3·w2·w1); boxes constant -> pipeline fully linear in proj.
//
// k_mainf: persistent double-buffered. 1024 blocks; block b owns n=b>>1 and
// 16 chunks of 16 channels (contiguous 100KB half-row). Per chunk: issue next
// chunk's loads -> compute current (bilinear idx/weights hoisted, chunk-
// invariant) -> scatter next -> ONE barrier. acc carries across chunks.
//
// ws layout (floats):
//   WH    [490][512]   off 0
//   Y     [512][512]   off 250880
//   T1    [490][512]   off 513024
//   Bmat  [490][512]   off 763904
//   u2    [512]        off 1014784
//   vv    [512]        off 1015296
//   dpart [10][8]      off 1015808
//   part  [1024*4][10] off 1015888

#define CHW4 25088   // float4 per proj row
#define STEP 1.8571428571428572f  // 13/7

// ---------- prep level 1: WH transpose (blocks 0..489) + u2=b2+w2*b1 (490..553)
__global__ __launch_bounds__(512) void k_prep1(
    const float* __restrict__ w_note, const float* __restrict__ w_reg,
    const float* __restrict__ w2, const float* __restrict__ b1,
    const float* __restrict__ b2,
    float* __restrict__ WH, float* __restrict__ u2) {
    int blk = blockIdx.x;
    int tid = threadIdx.x;
    if (blk < 490) {
        int k = blk / 49, ji = blk % 49;
        const float* wh = (k < 2) ? (w_note + k * 25088) : (w_reg + (k - 2) * 25088);
        WH[(size_t)blk * 512 + tid] = wh[tid * 49 + ji];
    } else {
        int wv = tid >> 6, lane = tid & 63;
        int o = (blk - 490) * 8 + wv;
        float s = 0.f;
        #pragma unroll
        for (int r = 0; r < 8; ++r) s += w2[(size_t)o * 512 + lane + r * 64] * b1[lane + r * 64];
        for (int off = 32; off; off >>= 1) s += __shfl_down(s, off);
        if (lane == 0) u2[o] = b2[o] + s;
    }
}

// ---------- prep level 2: {Y=w2*w1 | T1=WH*w3} (blocks 0..511) + vv=b3+w3*u2 (512..639)
__global__ __launch_bounds__(256) void k_prep2(
    const float* __restrict__ w1, const float* __restrict__ w2,
    const float* __restrict__ w3, const float* __restrict__ WH,
    const float* __restrict__ u2, const float* __restrict__ b3,
    float* __restrict__ Y, float* __restrict__ T1, float* __restrict__ vv) {
    int blk = blockIdx.x;
    int tid = threadIdx.x;
    if (blk < 512) {
        __shared__ float As[32][36];
        __shared__ float Bs[32][36];
        const float* A; const float* B; float* C; int M;
        if (blk < 256) { A = w2; B = w1; C = Y;  M = 512; }
        else           { A = WH; B = w3; C = T1; M = 490; }
        int t = blk & 255;
        int bx = t & 15, by = t >> 4;
        int lr = tid >> 3, lc = (tid & 7) << 2;
        int tx = tid & 15, ty = tid >> 4;
        float a00 = 0.f, a01 = 0.f, a10 = 0.f, a11 = 0.f;
        for (int kc = 0; kc < 512; kc += 32) {
            int gr = by * 32 + lr;
            float4 av = make_float4(0.f, 0.f, 0.f, 0.f);
            if (gr < M) av = *(const float4*)&A[(size_t)gr * 512 + kc + lc];
            *(float4*)&As[lr][lc] = av;
            *(float4*)&Bs[lr][lc] = *(const float4*)&B[(size_t)(kc + lr) * 512 + bx * 32 + lc];
            __syncthreads();
            #pragma unroll
            for (int kk = 0; kk < 32; ++kk) {
                float b0 = Bs[kk][tx * 2], b1v = Bs[kk][tx * 2 + 1];
                float x0 = As[ty * 2][kk], x1 = As[ty * 2 + 1][kk];
                a00 += x0 * b0; a01 += x0 * b1v;
                a10 += x1 * b0; a11 += x1 * b1v;
            }
            __syncthreads();
        }
        int r0 = by * 32 + ty * 2, c0 = bx * 32 + tx * 2;
        if (r0 < M)     { C[(size_t)r0 * 512 + c0] = a00; C[(size_t)r0 * 512 + c0 + 1] = a01; }
        if (r0 + 1 < M) { C[(size_t)(r0 + 1) * 512 + c0] = a10; C[(size_t)(r0 + 1) * 512 + c0 + 1] = a11; }
    } else {
        int wv = tid >> 6, lane = tid & 63;
        int o = (blk - 512) * 4 + wv;
        float s = 0.f;
        #pragma unroll
        for (int r = 0; r < 8; ++r) s += w3[(size_t)o * 512 + lane + r * 64] * u2[lane + r * 64];
        for (int off = 32; off; off >>= 1) s += __shfl_down(s, off);
        if (lane == 0) vv[o] = b3[o] + s;
    }
}

// ---------- prep level 3: Bmat=T1*Y (blocks 0..255) + dpart (256..335)
__global__ __launch_bounds__(256) void k_prep3(
    const float* __restrict__ T1, const float* __restrict__ Y,
    const float* __restrict__ w_note, const float* __restrict__ w_reg,
    const float* __restrict__ vv,
    float* __restrict__ Bmat, float* __restrict__ dpart) {
    int blk = blockIdx.x;
    int tid = threadIdx.x;
    if (blk < 256) {
        __shared__ float As[32][36];
        __shared__ float Bs[32][36];
        int bx = blk & 15, by = blk >> 4;
        int lr = tid >> 3, lc = (tid & 7) << 2;
        int tx = tid & 15, ty = tid >> 4;
        int gr = by * 32 + lr;
        float a00 = 0.f, a01 = 0.f, a10 = 0.f, a11 = 0.f;
        for (int kc = 0; kc < 512; kc += 32) {
            float4 av = make_float4(0.f, 0.f, 0.f, 0.f);
            if (gr < 490) av = *(const float4*)&T1[(size_t)gr * 512 + kc + lc];
            *(float4*)&As[lr][lc] = av;
            *(float4*)&Bs[lr][lc] = *(const float4*)&Y[(size_t)(kc + lr) * 512 + bx * 32 + lc];
            __syncthreads();
            #pragma unroll
            for (int kk = 0; kk < 32; ++kk) {
                float b0 = Bs[kk][tx * 2], b1v = Bs[kk][tx * 2 + 1];
                float x0 = As[ty * 2][kk], x1 = As[ty * 2 + 1][kk];
                a00 += x0 * b0; a01 += x0 * b1v;
                a10 += x1 * b0; a11 += x1 * b1v;
            }
            __syncthreads();
        }
        int r0 = by * 32 + ty * 2, c0 = bx * 32 + tx * 2;
        if (r0 < 490)     { Bmat[(size_t)r0 * 512 + c0] = a00; Bmat[(size_t)r0 * 512 + c0 + 1] = a01; }
        if (r0 + 1 < 490) { Bmat[(size_t)(r0 + 1) * 512 + c0] = a10; Bmat[(size_t)(r0 + 1) * 512 + c0 + 1] = a11; }
    } else {
        int t = blk - 256;             // 0..79
        int k = t >> 3, b8 = t & 7;
        const float* wh = (k < 2) ? (w_note + k * 25088) : (w_reg + (k - 2) * 25088);
        float s = 0.f;
        for (int i = b8 * 256 + tid; i < 25088; i += 2048) s += wh[i] * vv[i / 49];
        __shared__ float red[256];
        red[tid] = s;
        __syncthreads();
        for (int off = 128; off; off >>= 1) {
            if (tid < off) red[tid] += red[tid + off];
            __syncthreads();
        }
        if (tid == 0) dpart[k * 8 + b8] = red[0];
    }
}

// ---------- fused main, double-buffered persistent ----------
__global__ __launch_bounds__(256) void k_mainf(const float* __restrict__ proj,
                                               const float* __restrict__ Bmat,
                                               float* __restrict__ part) {
    __shared__ float X[2][16][197];   // 25,216 B
    int b = blockIdx.x;               // 0..1023
    int n = b >> 1;
    int ch0 = (b & 1) << 4;           // 0 or 16 (16-channel chunks, ch = ch0+t)
    int tid = threadIdx.x;
    int wv = tid >> 6, lane = tid & 63;

    // chunk-invariant staging scatter coords: i = tid + s*256 = cc*49 + q
    int cc0 = tid / 49,            q0 = tid - cc0 * 49;
    int cc1 = cc0 + 5,             q1 = q0 + 11; if (q1 >= 49) { q1 -= 49; ++cc1; }
    int cc2 = cc1 + 5,             q2 = q1 + 11; if (q2 >= 49) { q2 -= 49; ++cc2; }

    // chunk-invariant bilinear coords for slots s=0..2 (+ tail tid<16)
    const float base = STEP * 0.5f - 0.5f;
    int   i00s[4], bidx0s[4];
    float wxs[4], wys[4];
    #pragma unroll
    for (int s = 0; s < 4; ++s) {
        int o = tid + s * 256;
        if (o > 783) o = 783;          // dummy for inactive tail lanes
        int ji = o >> 4, cl = o & 15;
        int j = (ji * 37) >> 8;
        int i2 = ji - j * 7;
        float yv = base + j * STEP;
        float xv = base + i2 * STEP;
        float y0f = floorf(yv), x0f = floorf(xv);
        wys[s] = yv - y0f; wxs[s] = xv - x0f;
        i00s[s] = cl * 197 + (int)y0f * 14 + (int)x0f;
        bidx0s[s] = (ji << 9) + cl;    // + ch*16 at use
    }

    const float4* src0 = (const float4*)proj + (size_t)n * CHW4 + ch0 * 784;
    float acc[10];
    #pragma unroll
    for (int k = 0; k < 10; ++k) acc[k] = 0.f;

    // prologue: stage chunk 0 into buf 0
    {
        float4 v0 = src0[tid];
        float4 v1 = src0[tid + 256];
        float4 v2 = src0[tid + 512];
        float* xb = &X[0][0][0];
        *(float4*)&xb[cc0 * 197 + q0 * 4] = v0;
        *(float4*)&xb[cc1 * 197 + q1 * 4] = v1;
        *(float4*)&xb[cc2 * 197 + q2 * 4] = v2;
        if (tid < 16) *(float4*)&xb[15 * 197 + (tid + 33) * 4] = src0[tid + 768];
    }
    __syncthreads();

    int cur = 0;
    #pragma unroll 1
    for (int t = 0; t < 16; ++t) {
        // issue next chunk's loads early
        float4 v0, v1, v2, v3;
        if (t < 15) {
            const float4* sn = src0 + (t + 1) * 784;
            v0 = sn[tid]; v1 = sn[tid + 256]; v2 = sn[tid + 512];
            if (tid < 16) v3 = sn[tid + 768];
        }
        // compute current chunk
        const float* xb = &X[cur][0][0];
        int ch = ch0 + t;
        const float* Bc = Bmat + (ch << 4);
        #pragma unroll
        for (int s = 0; s < 3; ++s) {
            int i00 = i00s[s];
            float v00 = xb[i00],      v01 = xb[i00 + 1];
            float v10 = xb[i00 + 14], v11 = xb[i00 + 15];
            float top = v00 + (v01 - v00) * wxs[s];
            float bot = v10 + (v11 - v10) * wxs[s];
            float v = top + (bot - top) * wys[s];
            const float* Bp = Bc + bidx0s[s];
            #pragma unroll
            for (int k = 0; k < 10; ++k)
                acc[k] += v * Bp[(size_t)k * 25088];
        }
        if (tid < 16) {
            int i00 = i00s[3];
            float v00 = xb[i00],      v01 = xb[i00 + 1];
            float v10 = xb[i00 + 14], v11 = xb[i00 + 15];
            float top = v00 + (v01 - v00) * wxs[3];
            float bot = v10 + (v11 - v10) * wxs[3];
            float v = top + (bot - top) * wys[3];
            const float* Bp = Bc + bidx0s[3];
            #pragma unroll
            for (int k = 0; k < 10; ++k)
                acc[k] += v * Bp[(size_t)k * 25088];
        }
        // scatter next chunk into the other buffer
        if (t < 15) {
            float* xw = &X[cur ^ 1][0][0];
            *(float4*)&xw[cc0 * 197 + q0 * 4] = v0;
            *(float4*)&xw[cc1 * 197 + q1 * 4] = v1;
            *(float4*)&xw[cc2 * 197 + q2 * 4] = v2;
            if (tid < 16) *(float4*)&xw[15 * 197 + (tid + 33) * 4] = v3;
        }
        __syncthreads();
        cur ^= 1;
    }

    #pragma unroll
    for (int k = 0; k < 10; ++k) {
        float v = acc[k];
        v += __shfl_xor(v, 1);
        v += __shfl_xor(v, 2);
        v += __shfl_xor(v, 4);
        v += __shfl_xor(v, 8);
        v += __shfl_xor(v, 16);
        v += __shfl_xor(v, 32);
        if (lane == k) part[((size_t)b * 4 + wv) * 10 + k] = v;
    }
}

// out[n,k] = bias + dpart-sum + 8 wave-partials (2 halves x 4 waves)
__global__ void k_reduce(const float* __restrict__ part,
                         const float* __restrict__ dpart,
                         const float* __restrict__ b_note, const float* __restrict__ b_reg,
                         float* __restrict__ out) {
    int idx = blockIdx.x * 256 + threadIdx.x;  // 0..5119
    int n = idx / 10, k = idx % 10;
    float s = (k < 2) ? b_note[k] : b_reg[k - 2];
    for (int b = 0; b < 8; ++b) s += dpart[k * 8 + b];
    #pragma unroll
    for (int h = 0; h < 2; ++h)
        for (int w = 0; w < 4; ++w)
            s += part[(((size_t)(n * 2 + h)) * 4 + w) * 10 + k];
    if (k < 2) out[n * 2 + k] = s;
    else       out[1024 + n * 8 + (k - 2)] = s;
}

extern "C" void kernel_launch(void* const* d_in, const int* in_sizes, int n_in,
                              void* d_out, int out_size, void* d_ws, size_t ws_size,
                              hipStream_t stream) {
    const float* proj   = (const float*)d_in[0];
    const float* w1     = (const float*)d_in[1];
    const float* b1     = (const float*)d_in[2];
    const float* w2     = (const float*)d_in[3];
    const float* b2     = (const float*)d_in[4];
    const float* w3     = (const float*)d_in[5];
    const float* b3     = (const float*)d_in[6];
    const float* w_note = (const float*)d_in[7];
    const float* b_note = (const float*)d_in[8];
    const float* w_reg  = (const float*)d_in[9];
    const float* b_reg  = (const float*)d_in[10];

    float* ws    = (float*)d_ws;
    float* WH    = ws;
    float* Y     = WH + 250880;
    float* T1    = Y + 262144;
    float* Bmat  = T1 + 250880;
    float* u2    = Bmat + 250880;
    float* vv    = u2 + 512;
    float* dpart = vv + 512;
    float* part  = dpart + 80;
    float* out   = (float*)d_out;

    k_prep1<<<554, 512, 0, stream>>>(w_note, w_reg, w2, b1, b2, WH, u2);
    k_prep2<<<640, 256, 0, stream>>>(w1, w2, w3, WH, u2, b3, Y, T1, vv);
    k_prep3<<<336, 256, 0, stream>>>(T1, Y, w_note, w_reg, vv, Bmat, dpart);
    k_mainf<<<1024, 256, 0, stream>>>(proj, Bmat, part);
    k_reduce<<<20, 256, 0, stream>>>(part, dpart, b_note, b_reg, out);
}